// Round 1
// baseline (225.901 us; speedup 1.0000x reference)
//
#include <hip/hip_runtime.h>

#define RADIUS 8
#define LR 256
#define HRES 1024
#define NC 24
#define GF_EPS 1e-4f
#define STRIP 16

// ---------------- Kernel H: horizontal 17-tap window sums of I, p, I*p, I*I --------
// grid = NC*LR blocks (one per LR row), 256 threads (one per column)
__global__ __launch_bounds__(256) void kH(const float* __restrict__ p,
                                          const float* __restrict__ I,
                                          float* __restrict__ hI, float* __restrict__ hp,
                                          float* __restrict__ hIp, float* __restrict__ hII) {
    __shared__ float sI[LR];
    __shared__ float sp[LR];
    const int g = blockIdx.x;          // img*256 + y
    const int x = threadIdx.x;
    const int base = g * LR;
    sI[x] = I[base + x];
    sp[x] = p[base + x];
    __syncthreads();
    float aI = 0.f, ap = 0.f, aIp = 0.f, aII = 0.f;
    const int lo = max(x - RADIUS, 0);
    const int hi = min(x + RADIUS, LR - 1);
    #pragma unroll 1
    for (int xx = lo; xx <= hi; ++xx) {
        const float vi = sI[xx];
        const float vp = sp[xx];
        aI  += vi;
        ap  += vp;
        aIp += vi * vp;
        aII += vi * vi;
    }
    hI[base + x]  = aI;
    hp[base + x]  = ap;
    hIp[base + x] = aIp;
    hII[base + x] = aII;
}

// ---------------- Kernel V: vertical running-sum + guided-filter algebra ----------
// grid = NC * (LR/STRIP) blocks, 256 threads (one per column), each block does a
// 16-row strip with per-thread running column sums.
__global__ __launch_bounds__(256) void kV(const float* __restrict__ hI, const float* __restrict__ hp,
                                          const float* __restrict__ hIp, const float* __restrict__ hII,
                                          float* __restrict__ A, float* __restrict__ B) {
    const int x     = threadIdx.x;
    const int img   = blockIdx.x / (LR / STRIP);
    const int strip = blockIdx.x % (LR / STRIP);
    const int y0    = strip * STRIP;
    const int ib    = img * LR * LR;

    float sI = 0.f, sp_ = 0.f, sIp = 0.f, sII = 0.f;
    #pragma unroll 1
    for (int yy = y0 - RADIUS; yy <= y0 + RADIUS; ++yy) {
        if (yy >= 0 && yy < LR) {
            const int idx = ib + yy * LR + x;
            sI  += hI[idx];
            sp_ += hp[idx];
            sIp += hIp[idx];
            sII += hII[idx];
        }
    }
    const int cntx = min(x + RADIUS, LR - 1) - max(x - RADIUS, 0) + 1;
    #pragma unroll 1
    for (int y = y0; y < y0 + STRIP; ++y) {
        const int cnty = min(y + RADIUS, LR - 1) - max(y - RADIUS, 0) + 1;
        const float inv = 1.0f / (float)(cntx * cnty);
        const float mI  = sI  * inv;
        const float mp  = sp_ * inv;
        const float mIp = sIp * inv;
        const float mII = sII * inv;
        const float cov = mIp - mI * mp;
        const float var = mII - mI * mI;
        const float a   = cov / (var + GF_EPS);
        const float b   = mp - a * mI;
        const int idx = ib + y * LR + x;
        A[idx] = a;
        B[idx] = b;
        const int yadd = y + RADIUS + 1;
        const int ysub = y - RADIUS;
        if (yadd < LR) {
            const int ia = ib + yadd * LR + x;
            sI += hI[ia]; sp_ += hp[ia]; sIp += hIp[ia]; sII += hII[ia];
        }
        if (ysub >= 0) {
            const int is = ib + ysub * LR + x;
            sI -= hI[is]; sp_ -= hp[is]; sIp -= hIp[is]; sII -= hII[is];
        }
    }
}

// ---------------- Kernel R: bilinear x4 upsample of A,B fused with A*I_hr + B -----
// grid = NC*HRES blocks (one per HR row), 256 threads; each thread does 4 consecutive
// x pixels (one float4). src coord = 0.25*dst - 0.375 (half-pixel centers), edge clamp.
__global__ __launch_bounds__(256) void kR(const float* __restrict__ A, const float* __restrict__ B,
                                          const float* __restrict__ Ihr, float* __restrict__ out) {
    const int b   = blockIdx.x;        // img*1024 + y
    const int tx  = threadIdx.x;       // x-group index; LR column "center" = tx
    const int y   = b & (HRES - 1);

    float sy = fminf(fmaxf(0.25f * (float)y - 0.375f, 0.0f), (float)(LR - 1));
    const int y0 = (int)sy;
    const float fy = sy - (float)y0;
    const int y1 = min(y0 + 1, LR - 1);

    const int img = b >> 10;
    const float* Ai = A + img * LR * LR;
    const float* Bi = B + img * LR * LR;
    const int cm1 = max(tx - 1, 0);
    const int cp1 = min(tx + 1, LR - 1);

    const float a0m = Ai[y0 * LR + cm1], a0c = Ai[y0 * LR + tx], a0p = Ai[y0 * LR + cp1];
    const float a1m = Ai[y1 * LR + cm1], a1c = Ai[y1 * LR + tx], a1p = Ai[y1 * LR + cp1];
    const float b0m = Bi[y0 * LR + cm1], b0c = Bi[y0 * LR + tx], b0p = Bi[y0 * LR + cp1];
    const float b1m = Bi[y1 * LR + cm1], b1c = Bi[y1 * LR + tx], b1p = Bi[y1 * LR + cp1];

    // vertical lerp first (bilinear is separable; order-independent)
    const float am = a0m + fy * (a1m - a0m);
    const float ac = a0c + fy * (a1c - a0c);
    const float ap = a0p + fy * (a1p - a0p);
    const float bm = b0m + fy * (b1m - b0m);
    const float bc = b0c + fy * (b1c - b0c);
    const float bp = b0p + fy * (b1p - b0p);

    // horizontal phases: t=0: lerp(am,ac,0.625) t=1: lerp(am,ac,0.875)
    //                    t=2: lerp(ac,ap,0.125) t=3: lerp(ac,ap,0.375)
    // tx==0: src x < 0 for t=0,1 -> clamps to column 0 (== ac)
    float a_t0, a_t1, b_t0, b_t1;
    if (tx == 0) {
        a_t0 = ac; a_t1 = ac; b_t0 = bc; b_t1 = bc;
    } else {
        a_t0 = am + 0.625f * (ac - am);
        a_t1 = am + 0.875f * (ac - am);
        b_t0 = bm + 0.625f * (bc - bm);
        b_t1 = bm + 0.875f * (bc - bm);
    }
    // tx==255: cp1==tx so ap==ac, formulas degenerate to ac (correct clamp)
    const float a_t2 = ac + 0.125f * (ap - ac);
    const float a_t3 = ac + 0.375f * (ap - ac);
    const float b_t2 = bc + 0.125f * (bp - bc);
    const float b_t3 = bc + 0.375f * (bp - bc);

    const long long o = ((long long)b << 10) + (tx << 2);
    const float4 ih = *(const float4*)(Ihr + o);
    float4 r;
    r.x = a_t0 * ih.x + b_t0;
    r.y = a_t1 * ih.y + b_t1;
    r.z = a_t2 * ih.z + b_t2;
    r.w = a_t3 * ih.w + b_t3;
    *(float4*)(out + o) = r;
}

extern "C" void kernel_launch(void* const* d_in, const int* in_sizes, int n_in,
                              void* d_out, int out_size, void* d_ws, size_t ws_size,
                              hipStream_t stream) {
    const float* p_lr = (const float*)d_in[0];
    const float* I_lr = (const float*)d_in[1];
    const float* I_hr = (const float*)d_in[2];
    float* out = (float*)d_out;
    float* ws  = (float*)d_ws;

    const int S = NC * LR * LR;   // 1,572,864 floats per plane
    float* hI  = ws + 0 * (size_t)S;
    float* hp  = ws + 1 * (size_t)S;
    float* hIp = ws + 2 * (size_t)S;
    float* hII = ws + 3 * (size_t)S;
    float* A   = ws + 4 * (size_t)S;
    float* B   = ws + 5 * (size_t)S;

    kH<<<NC * LR, 256, 0, stream>>>(p_lr, I_lr, hI, hp, hIp, hII);
    kV<<<NC * (LR / STRIP), 256, 0, stream>>>(hI, hp, hIp, hII, A, B);
    kR<<<NC * HRES, 256, 0, stream>>>(A, B, I_hr, out);
}

// Round 2
// 219.900 us; speedup vs baseline: 1.0273x; 1.0273x over previous
//
#include <hip/hip_runtime.h>

#define RADIUS 8
#define LR 256
#define HRES 1024
#define NC 24
#define GF_EPS 1e-4f
#define STRIP 4   // kV rows per block: 24*64=1536 blocks -> 6 waves/SIMD

// ---------------- Kernel H: horizontal 17-tap window sums of I, p, I*p, I*I --------
// grid = NC*LR blocks (one per LR row), 256 threads (one per column)
__global__ __launch_bounds__(256) void kH(const float* __restrict__ p,
                                          const float* __restrict__ I,
                                          float* __restrict__ hI, float* __restrict__ hp,
                                          float* __restrict__ hIp, float* __restrict__ hII) {
    __shared__ float sI[LR];
    __shared__ float sp[LR];
    const int g = blockIdx.x;          // img*256 + y
    const int x = threadIdx.x;
    const int base = g * LR;
    sI[x] = I[base + x];
    sp[x] = p[base + x];
    __syncthreads();
    float aI = 0.f, ap = 0.f, aIp = 0.f, aII = 0.f;
    const int lo = max(x - RADIUS, 0);
    const int hi = min(x + RADIUS, LR - 1);
    #pragma unroll 1
    for (int xx = lo; xx <= hi; ++xx) {
        const float vi = sI[xx];
        const float vp = sp[xx];
        aI  += vi;
        ap  += vp;
        aIp += vi * vp;
        aII += vi * vi;
    }
    hI[base + x]  = aI;
    hp[base + x]  = ap;
    hIp[base + x] = aIp;
    hII[base + x] = aII;
}

// ---------------- Kernel V: vertical running-sum + guided-filter algebra ----------
// grid = NC * (LR/STRIP) blocks, 256 threads (one per column), each block does a
// STRIP-row strip with per-thread running column sums.
__global__ __launch_bounds__(256) void kV(const float* __restrict__ hI, const float* __restrict__ hp,
                                          const float* __restrict__ hIp, const float* __restrict__ hII,
                                          float* __restrict__ A, float* __restrict__ B) {
    const int x     = threadIdx.x;
    const int img   = blockIdx.x / (LR / STRIP);
    const int strip = blockIdx.x % (LR / STRIP);
    const int y0    = strip * STRIP;
    const int ib    = img * LR * LR;

    float sI = 0.f, sp_ = 0.f, sIp = 0.f, sII = 0.f;
    #pragma unroll 1
    for (int yy = y0 - RADIUS; yy <= y0 + RADIUS; ++yy) {
        if (yy >= 0 && yy < LR) {
            const int idx = ib + yy * LR + x;
            sI  += hI[idx];
            sp_ += hp[idx];
            sIp += hIp[idx];
            sII += hII[idx];
        }
    }
    const int cntx = min(x + RADIUS, LR - 1) - max(x - RADIUS, 0) + 1;
    #pragma unroll
    for (int y = y0; y < y0 + STRIP; ++y) {
        const int cnty = min(y + RADIUS, LR - 1) - max(y - RADIUS, 0) + 1;
        const float inv = 1.0f / (float)(cntx * cnty);
        const float mI  = sI  * inv;
        const float mp  = sp_ * inv;
        const float mIp = sIp * inv;
        const float mII = sII * inv;
        const float cov = mIp - mI * mp;
        const float var = mII - mI * mI;
        const float a   = cov / (var + GF_EPS);
        const float b   = mp - a * mI;
        const int idx = ib + y * LR + x;
        A[idx] = a;
        B[idx] = b;
        const int yadd = y + RADIUS + 1;
        const int ysub = y - RADIUS;
        if (yadd < LR) {
            const int ia = ib + yadd * LR + x;
            sI += hI[ia]; sp_ += hp[ia]; sIp += hIp[ia]; sII += hII[ia];
        }
        if (ysub >= 0) {
            const int is = ib + ysub * LR + x;
            sI -= hI[is]; sp_ -= hp[is]; sIp -= hII[is] * 0.f + hIp[is]; sII -= hII[is];
        }
    }
}

// ---------------- Kernel R: bilinear x4 upsample of A,B fused with A*I_hr + B -----
// One block per (img, group of 4 HR rows) = one LR row index k. grid = NC*256.
// HR rows 4k..4k+3 use LR row pairs: r0,r1 phases
//   y=4k  : (k-1, k) fy=0.625   y=4k+1: (k-1, k) fy=0.875
//   y=4k+2: (k, k+1) fy=0.125   y=4k+3: (k, k+1) fy=0.375   (rows clamped to [0,255])
// Stage vertically-lerped av/bv rows for the 4 phases in LDS, then each thread
// streams 4 float4 I_hr/out pairs (one per HR row) -> 4-deep VMEM ILP.
__global__ __launch_bounds__(256) void kR(const float* __restrict__ A, const float* __restrict__ B,
                                          const float* __restrict__ Ihr, float* __restrict__ out) {
    __shared__ float av[4][LR];
    __shared__ float bv[4][LR];

    const int blk = blockIdx.x;
    const int img = blk >> 8;          // /256
    const int k   = blk & 255;
    const int tx  = threadIdx.x;

    const float* Ai = A + img * LR * LR;
    const float* Bi = B + img * LR * LR;
    const int km = max(k - 1, 0);
    const int kp = min(k + 1, LR - 1);

    const float aU = Ai[km * LR + tx];   // row k-1 (clamped)
    const float aC = Ai[k  * LR + tx];   // row k
    const float aD = Ai[kp * LR + tx];   // row k+1 (clamped)
    const float bU = Bi[km * LR + tx];
    const float bC = Bi[k  * LR + tx];
    const float bD = Bi[kp * LR + tx];

    av[0][tx] = aU + 0.625f * (aC - aU);
    av[1][tx] = aU + 0.875f * (aC - aU);
    av[2][tx] = aC + 0.125f * (aD - aC);
    av[3][tx] = aC + 0.375f * (aD - aC);
    bv[0][tx] = bU + 0.625f * (bC - bU);
    bv[1][tx] = bU + 0.875f * (bC - bU);
    bv[2][tx] = bC + 0.125f * (bD - bC);
    bv[3][tx] = bC + 0.375f * (bD - bC);
    __syncthreads();

    const int cm1 = max(tx - 1, 0);
    const int cp1 = min(tx + 1, LR - 1);
    const long long rowbase = ((long long)img << 20) + ((long long)k << 12) + (tx << 2);

    #pragma unroll
    for (int r = 0; r < 4; ++r) {
        const float am = av[r][cm1], ac = av[r][tx], ap = av[r][cp1];
        const float bm = bv[r][cm1], bc = bv[r][tx], bp = bv[r][cp1];
        // horizontal phases for the 4 pixels of this thread:
        // t0: lerp(am,ac,0.625) t1: lerp(am,ac,0.875) t2: lerp(ac,ap,0.125) t3: lerp(ac,ap,0.375)
        float a0, a1, b0, b1;
        if (tx == 0) { a0 = ac; a1 = ac; b0 = bc; b1 = bc; }  // x<0 clamps to col 0
        else {
            a0 = am + 0.625f * (ac - am);
            a1 = am + 0.875f * (ac - am);
            b0 = bm + 0.625f * (bc - bm);
            b1 = bm + 0.875f * (bc - bm);
        }
        const float a2 = ac + 0.125f * (ap - ac);   // tx==255: ap==ac -> clamp ok
        const float a3 = ac + 0.375f * (ap - ac);
        const float b2 = bc + 0.125f * (bp - bc);
        const float b3 = bc + 0.375f * (bp - bc);

        const long long o = rowbase + ((long long)r << 10);
        const float4 ih = *(const float4*)(Ihr + o);
        float4 res;
        res.x = a0 * ih.x + b0;
        res.y = a1 * ih.y + b1;
        res.z = a2 * ih.z + b2;
        res.w = a3 * ih.w + b3;
        *(float4*)(out + o) = res;
    }
}

extern "C" void kernel_launch(void* const* d_in, const int* in_sizes, int n_in,
                              void* d_out, int out_size, void* d_ws, size_t ws_size,
                              hipStream_t stream) {
    const float* p_lr = (const float*)d_in[0];
    const float* I_lr = (const float*)d_in[1];
    const float* I_hr = (const float*)d_in[2];
    float* out = (float*)d_out;
    float* ws  = (float*)d_ws;

    const int S = NC * LR * LR;   // 1,572,864 floats per plane
    float* hI  = ws + 0 * (size_t)S;
    float* hp  = ws + 1 * (size_t)S;
    float* hIp = ws + 2 * (size_t)S;
    float* hII = ws + 3 * (size_t)S;
    float* A   = ws + 4 * (size_t)S;
    float* B   = ws + 5 * (size_t)S;

    kH<<<NC * LR, 256, 0, stream>>>(p_lr, I_lr, hI, hp, hIp, hII);
    kV<<<NC * (LR / STRIP), 256, 0, stream>>>(hI, hp, hIp, hII, A, B);
    kR<<<NC * 256, 256, 0, stream>>>(A, B, I_hr, out);
}

// Round 4
// 211.933 us; speedup vs baseline: 1.0659x; 1.0376x over previous
//
#include <hip/hip_runtime.h>

#define RADIUS 8
#define LR 256
#define HRES 1024
#define NC 24
#define GF_EPS 1e-4f
#define STRIP 4   // kV rows per block: 24*64=1536 blocks

typedef float f4 __attribute__((ext_vector_type(4)));  // native vector: nontemporal-builtin legal

// ---------------- Kernel H: horizontal 17-tap window sums of I, p, I*p, I*I --------
// grid = NC*LR blocks (one per LR row), 256 threads (one per column)
__global__ __launch_bounds__(256) void kH(const float* __restrict__ p,
                                          const float* __restrict__ I,
                                          float* __restrict__ hI, float* __restrict__ hp,
                                          float* __restrict__ hIp, float* __restrict__ hII) {
    __shared__ float sI[LR];
    __shared__ float sp[LR];
    const int g = blockIdx.x;          // img*256 + y
    const int x = threadIdx.x;
    const int base = g * LR;
    sI[x] = I[base + x];
    sp[x] = p[base + x];
    __syncthreads();
    float aI = 0.f, ap = 0.f, aIp = 0.f, aII = 0.f;
    const int lo = max(x - RADIUS, 0);
    const int hi = min(x + RADIUS, LR - 1);
    #pragma unroll 1
    for (int xx = lo; xx <= hi; ++xx) {
        const float vi = sI[xx];
        const float vp = sp[xx];
        aI  += vi;
        ap  += vp;
        aIp += vi * vp;
        aII += vi * vi;
    }
    hI[base + x]  = aI;
    hp[base + x]  = ap;
    hIp[base + x] = aIp;
    hII[base + x] = aII;
}

// ---------------- Kernel V: vertical running-sum + guided-filter algebra ----------
__global__ __launch_bounds__(256) void kV(const float* __restrict__ hI, const float* __restrict__ hp,
                                          const float* __restrict__ hIp, const float* __restrict__ hII,
                                          float* __restrict__ A, float* __restrict__ B) {
    const int x     = threadIdx.x;
    const int img   = blockIdx.x / (LR / STRIP);
    const int strip = blockIdx.x % (LR / STRIP);
    const int y0    = strip * STRIP;
    const int ib    = img * LR * LR;

    float sI = 0.f, sp_ = 0.f, sIp = 0.f, sII = 0.f;
    #pragma unroll 1
    for (int yy = y0 - RADIUS; yy <= y0 + RADIUS; ++yy) {
        if (yy >= 0 && yy < LR) {
            const int idx = ib + yy * LR + x;
            sI  += hI[idx];
            sp_ += hp[idx];
            sIp += hIp[idx];
            sII += hII[idx];
        }
    }
    const int cntx = min(x + RADIUS, LR - 1) - max(x - RADIUS, 0) + 1;
    #pragma unroll
    for (int y = y0; y < y0 + STRIP; ++y) {
        const int cnty = min(y + RADIUS, LR - 1) - max(y - RADIUS, 0) + 1;
        const float inv = 1.0f / (float)(cntx * cnty);
        const float mI  = sI  * inv;
        const float mp  = sp_ * inv;
        const float mIp = sIp * inv;
        const float mII = sII * inv;
        const float cov = mIp - mI * mp;
        const float var = mII - mI * mI;
        const float a   = cov / (var + GF_EPS);
        const float b   = mp - a * mI;
        const int idx = ib + y * LR + x;
        A[idx] = a;
        B[idx] = b;
        const int yadd = y + RADIUS + 1;
        const int ysub = y - RADIUS;
        if (yadd < LR) {
            const int ia = ib + yadd * LR + x;
            sI += hI[ia]; sp_ += hp[ia]; sIp += hIp[ia]; sII += hII[ia];
        }
        if (ysub >= 0) {
            const int is = ib + ysub * LR + x;
            sI -= hI[is]; sp_ -= hp[is]; sIp -= hIp[is]; sII -= hII[is];
        }
    }
}

// ---------------- Kernel R: bilinear x4 upsample of A,B fused with A*I_hr + B -----
// One block per (img, PAIR of LR rows k,k+1) -> 8 HR rows. grid = NC*128.
// Stage the 8 vertically-lerped phase rows of A,B in LDS, then each thread issues
// ALL 8 float4 I_hr loads up-front (register array, nontemporal) before computing
// and storing -> 8 KB outstanding per wave, deep MLP.
// Phase table (HR row 8*k2+r, k=2*k2), rows clamped to [0,255]:
//   r=0: lerp(A[k-1],A[k],.625)   r=1: .875
//   r=2: lerp(A[k],A[k+1],.125)   r=3: .375
//   r=4: lerp(A[k],A[k+1],.625)   r=5: .875
//   r=6: lerp(A[k+1],A[k+2],.125) r=7: .375
__global__ __launch_bounds__(256) void kR(const float* __restrict__ A, const float* __restrict__ B,
                                          const float* __restrict__ Ihr, float* __restrict__ out) {
    __shared__ float av[8][LR];
    __shared__ float bv[8][LR];

    const int blk = blockIdx.x;
    const int img = blk >> 7;          // /128
    const int k2  = blk & 127;
    const int k   = k2 << 1;
    const int tx  = threadIdx.x;

    const float* Ai = A + img * LR * LR;
    const float* Bi = B + img * LR * LR;
    const int rm = max(k - 1, 0);
    const int rp = min(k + 2, LR - 1);

    const float aU = Ai[rm * LR + tx];        // row k-1 (clamped)
    const float a0 = Ai[k * LR + tx];         // row k
    const float a1 = Ai[(k + 1) * LR + tx];   // row k+1
    const float aD = Ai[rp * LR + tx];        // row k+2 (clamped)
    const float bU = Bi[rm * LR + tx];
    const float b0 = Bi[k * LR + tx];
    const float b1 = Bi[(k + 1) * LR + tx];
    const float bD = Bi[rp * LR + tx];

    av[0][tx] = aU + 0.625f * (a0 - aU);
    av[1][tx] = aU + 0.875f * (a0 - aU);
    av[2][tx] = a0 + 0.125f * (a1 - a0);
    av[3][tx] = a0 + 0.375f * (a1 - a0);
    av[4][tx] = a0 + 0.625f * (a1 - a0);
    av[5][tx] = a0 + 0.875f * (a1 - a0);
    av[6][tx] = a1 + 0.125f * (aD - a1);
    av[7][tx] = a1 + 0.375f * (aD - a1);
    bv[0][tx] = bU + 0.625f * (b0 - bU);
    bv[1][tx] = bU + 0.875f * (b0 - bU);
    bv[2][tx] = b0 + 0.125f * (b1 - b0);
    bv[3][tx] = b0 + 0.375f * (b1 - b0);
    bv[4][tx] = b0 + 0.625f * (b1 - b0);
    bv[5][tx] = b0 + 0.875f * (b1 - b0);
    bv[6][tx] = b1 + 0.125f * (bD - b1);
    bv[7][tx] = b1 + 0.375f * (bD - b1);
    __syncthreads();

    // HR row 4k has offset (4k)<<10 = k<<12 within the image.
    const long long base = ((long long)img << 20) + ((long long)k << 12) + (tx << 2);

    f4 ih[8];
    #pragma unroll
    for (int r = 0; r < 8; ++r)
        ih[r] = __builtin_nontemporal_load((const f4*)(Ihr + base + ((long long)r << 10)));

    const int cm1 = max(tx - 1, 0);
    const int cp1 = min(tx + 1, LR - 1);

    #pragma unroll
    for (int r = 0; r < 8; ++r) {
        const float am = av[r][cm1], ac = av[r][tx], ap = av[r][cp1];
        const float bm = bv[r][cm1], bc = bv[r][tx], bp = bv[r][cp1];
        float p0, p1, q0, q1;
        if (tx == 0) { p0 = ac; p1 = ac; q0 = bc; q1 = bc; }  // x<0 clamps to col 0
        else {
            p0 = am + 0.625f * (ac - am);
            p1 = am + 0.875f * (ac - am);
            q0 = bm + 0.625f * (bc - bm);
            q1 = bm + 0.875f * (bc - bm);
        }
        const float p2 = ac + 0.125f * (ap - ac);   // tx==255: ap==ac -> clamp ok
        const float p3 = ac + 0.375f * (ap - ac);
        const float q2 = bc + 0.125f * (bp - bc);
        const float q3 = bc + 0.375f * (bp - bc);

        f4 res;
        res.x = p0 * ih[r].x + q0;
        res.y = p1 * ih[r].y + q1;
        res.z = p2 * ih[r].z + q2;
        res.w = p3 * ih[r].w + q3;
        __builtin_nontemporal_store(res, (f4*)(out + base + ((long long)r << 10)));
    }
}

extern "C" void kernel_launch(void* const* d_in, const int* in_sizes, int n_in,
                              void* d_out, int out_size, void* d_ws, size_t ws_size,
                              hipStream_t stream) {
    const float* p_lr = (const float*)d_in[0];
    const float* I_lr = (const float*)d_in[1];
    const float* I_hr = (const float*)d_in[2];
    float* out = (float*)d_out;
    float* ws  = (float*)d_ws;

    const int S = NC * LR * LR;   // 1,572,864 floats per plane
    float* hI  = ws + 0 * (size_t)S;
    float* hp  = ws + 1 * (size_t)S;
    float* hIp = ws + 2 * (size_t)S;
    float* hII = ws + 3 * (size_t)S;
    float* A   = ws + 4 * (size_t)S;
    float* B   = ws + 5 * (size_t)S;

    kH<<<NC * LR, 256, 0, stream>>>(p_lr, I_lr, hI, hp, hIp, hII);
    kV<<<NC * (LR / STRIP), 256, 0, stream>>>(hI, hp, hIp, hII, A, B);
    kR<<<NC * 128, 256, 0, stream>>>(A, B, I_hr, out);
}